// Round 6
// baseline (448.334 us; speedup 1.0000x reference)
//
#include <hip/hip_runtime.h>
#include <cstdint>
#include <cstddef>

#define BB 8
#define SS 1024
#define EE 512
#define NQB 16
#define FF 2048

typedef unsigned short u16;
typedef __attribute__((ext_vector_type(8))) short short8;
typedef __attribute__((ext_vector_type(4))) float f32x4;
typedef unsigned int uint_g __attribute__((address_space(1)));
typedef unsigned int uint_l __attribute__((address_space(3)));

// ---- ws layout (bytes). Proven budget: ws >= 18 MiB.
#define FLAG_OFF   0
#define H16_OFF    4096                    // 8192*16*4 = 512 KiB (post-LN1 dims 0..15)
#define QF_OFF     528384                  // 512 KiB
#define W1P_OFF    1052672                 // 256 KiB
#define STATS_OFF  1314816                 // 256 KiB
#define H_OFF      2097152                 // 16 MiB (ends at 18 MiB)
#define W2P_OFF    18874368                // 8 MiB, only if ws >= 26 MiB

__device__ __forceinline__ float u2f(u16 u){ return __uint_as_float(((unsigned)u)<<16); }
__device__ __forceinline__ u16 f2bf(float x){
  unsigned u = __float_as_uint(x);
  u += 0x7FFF + ((u>>16)&1);   // RNE
  return (u16)(u>>16);
}
__device__ __forceinline__ float ldg(const void* p,int f,size_t i){
  return f ? ((const float*)p)[i] : u2f(((const u16*)p)[i]);
}
__device__ __forceinline__ float4 ldg4(const void* p,int f,size_t i){ // i mult of 4
  float4 r;
  if (f){ r = ((const float4*)p)[i>>2]; }
  else { ushort4 v = ((const ushort4*)p)[i>>2];
         r.x=u2f(v.x); r.y=u2f(v.y); r.z=u2f(v.z); r.w=u2f(v.w); }
  return r;
}
__device__ __forceinline__ short8 ldfrag8(const void* p,int f,size_t i){ // i mult of 8
  short8 r;
  if (f){
    float4 A  = ((const float4*)p)[i>>2];
    float4 Bv = ((const float4*)p)[(i>>2)+1];
    r[0]=(short)f2bf(A.x);  r[1]=(short)f2bf(A.y);  r[2]=(short)f2bf(A.z);  r[3]=(short)f2bf(A.w);
    r[4]=(short)f2bf(Bv.x); r[5]=(short)f2bf(Bv.y); r[6]=(short)f2bf(Bv.z); r[7]=(short)f2bf(Bv.w);
  } else {
    r = *(const short8*)((const u16*)p + i);
  }
  return r;
}
__device__ __forceinline__ void async16(const void* g, void* l){
  __builtin_amdgcn_global_load_lds((const uint_g*)g, (uint_l*)l, 16, 0, 0);
}
__device__ __forceinline__ void tok_stats(const float* st, int tok, float& m, float& rs){
  float S1 = 0.f, S2 = 0.f;
  #pragma unroll
  for (int nb=0; nb<4; ++nb){
    float2 p = *(const float2*)&st[((size_t)tok*4+nb)*2];
    S1 += p.x; S2 += p.y;
  }
  m = S1*(1.f/512.f);
  float var = S2*(1.f/512.f) - m*m;
  rs = rsqrtf(var + 1e-5f);
}

__global__ void detect_k(const u16* __restrict__ x, int* __restrict__ flag){
  __shared__ int cnt;
  if (threadIdx.x==0) cnt=0;
  __syncthreads();
  int c=0;
  for (int i=threadIdx.x;i<4096;i+=256){
    u16 v = x[(size_t)i*2];
    int ex = (v>>7)&0xFF;
    c += (ex>=160) ? 1 : 0;
  }
  atomicAdd(&cnt,c);
  __syncthreads();
  if (threadIdx.x==0) *flag = (cnt>64) ? 1 : 0;
}

__global__ __launch_bounds__(256) void w1pack_k(const void* __restrict__ W1,
    const void* __restrict__ thf, u16* __restrict__ W1p, const int* __restrict__ flag){
  int f = *flag;
  int idx = blockIdx.x*256 + threadIdx.x;        // 0..16383
  int l = idx>>12, nt = (idx>>5)&127, lane32 = idx&31;
  int quad = lane32>>4, col = lane32&15;
  short8 v = ldfrag8(W1, f, ((size_t)l*FF + nt*16 + col)*16 + quad*8);
  short8 o;
  #pragma unroll
  for (int j=0;j<8;++j){
    float th = ldg(thf, f, (size_t)l*16 + quad*8 + j);
    o[j] = (short)f2bf(__cosf(th) * u2f((u16)v[j]));
  }
  *(short8*)(W1p + (size_t)idx*8) = o;
}

__global__ __launch_bounds__(256) void w2pack_k(const void* __restrict__ W2,
    u16* __restrict__ W2p, const int* __restrict__ flag){
  int f = *flag;
  int idx = blockIdx.x*256 + threadIdx.x;        // 0..524287
  int lane = idx&63, kb = (idx>>6)&63, teg = (idx>>12)&31, l = idx>>17;
  int quad = lane>>4, col = lane&15;
  short8 v = ldfrag8(W2, f, ((size_t)l*EE + teg*16 + col)*FF + kb*32 + quad*8);
  *(short8*)(W2p + (size_t)idx*8) = v;
}

__global__ __launch_bounds__(256) void add_pe_k(const void* __restrict__ x,
    const void* __restrict__ pe, float* __restrict__ hw, const int* __restrict__ flag){
  int f = *flag;
  size_t e = ((size_t)blockIdx.x*256 + threadIdx.x)*4;
  float4 xv = ldg4(x,f,e);
  float4 pv = ldg4(pe,f,e & (size_t)(SS*EE-1));
  float4 o; o.x=xv.x+pv.x; o.y=xv.y+pv.y; o.z=xv.z+pv.z; o.w=xv.w+pv.w;
  *(float4*)&hw[e] = o;
}

// ===== fused attention + combine + LN1. grid 256 = 8 b x 32 groups of 32 rows.
// Phase A: stage quantum key features qq[1024][16] for this b (lazy LN2).
// Phase B: softmax loop, thread = (row, head), broadcast LDS reads.
// Phase C: attn @ Wc^T + residual + LN1; dims>=16 -> hw, dims<16 -> h16 + qf.
__global__ __launch_bounds__(256) void attn_comb_k(float* __restrict__ hw,
    const void* __restrict__ thA, const void* __restrict__ Wc,
    const void* __restrict__ g1v, const void* __restrict__ b1v,
    const void* __restrict__ g2v, const void* __restrict__ b2v,
    const float* __restrict__ st, float* __restrict__ h16,
    float* __restrict__ qf, const int* __restrict__ flag, int lazy, int l){
  __shared__ float SM2[19264];
  float* qq   = SM2;             // [1024][16] (A/B) — overlaid by outC in C
  float* outC = SM2;             // [32][520]
  float* msK  = SM2 + 16640;     // [1024][2]
  float* AFR  = SM2 + 18688;     // [32][16]
  float* MS   = SM2 + 19200;     // [32]
  float* RS   = SM2 + 19232;     // [32]
  int f = *flag;
  int tid = threadIdx.x;
  int b = blockIdx.x>>5, grp = blockIdx.x&31;
  size_t bbase = (size_t)b*SS*EE;
  int tok0 = b*SS + grp*32;

  if (lazy){
    #pragma unroll
    for (int t2=0;t2<4;++t2){
      int j = tid*4+t2;
      float m, rs; tok_stats(st, b*SS+j, m, rs);
      msK[j*2]=m; msK[j*2+1]=rs;
    }
  }
  __syncthreads();
  { // Phase A: 4 threads per token, 4 dims each
    int j0 = tid>>2, d0 = (tid&3)*4;
    float ct[4], gl2[4]={1,1,1,1}, bl2[4]={0,0,0,0};
    #pragma unroll
    for (int d=0;d<4;++d) ct[d] = __cosf(ldg(thA,f,(size_t)l*16+d0+d));
    if (lazy){
      float4 gv = ldg4(g2v,f,(size_t)(l-1)*EE+d0);
      float4 bv = ldg4(b2v,f,(size_t)(l-1)*EE+d0);
      gl2[0]=gv.x; gl2[1]=gv.y; gl2[2]=gv.z; gl2[3]=gv.w;
      bl2[0]=bv.x; bl2[1]=bv.y; bl2[2]=bv.z; bl2[3]=bv.w;
    }
    for (int it=0; it<16; ++it){
      int j = j0 + it*64;
      float4 hv = *(const float4*)&hw[bbase + (size_t)j*EE + d0];
      float vv[4] = {hv.x, hv.y, hv.z, hv.w};
      if (lazy){
        float m = msK[j*2], rs = msK[j*2+1];
        #pragma unroll
        for (int d=0;d<4;++d) vv[d] = fmaf((vv[d]-m)*rs, gl2[d], bl2[d]);
      }
      float4 o;
      o.x = ct[0]*__cosf(vv[0]); o.y = ct[1]*__cosf(vv[1]);
      o.z = ct[2]*__cosf(vv[2]); o.w = ct[3]*__cosf(vv[3]);
      *(float4*)&qq[j*16+d0] = o;
    }
  }
  __syncthreads();
  { // Phase B: softmax, |score| <= sqrt(2) -> plain exp
    int r = tid&31, hd = tid>>5;
    int rg = grp*32 + r;
    float a0 = qq[rg*16 + 2*hd], a1 = qq[rg*16 + 2*hd + 1];
    const float sc = 0.70710678118f;
    float a0s = a0*sc, a1s = a1*sc;
    float den=0.f, n0=0.f, n1=0.f;
    for (int j=0;j<SS;++j){
      float2 uv = *(const float2*)&qq[j*16 + 2*hd];
      float e = __expf(fmaf(a1s, uv.y, a0s*uv.x));
      den += e; n0 = fmaf(e, uv.x, n0); n1 = fmaf(e, uv.y, n1);
    }
    float inv = 1.f/den;
    AFR[r*16 + 2*hd] = n0*inv; AFR[r*16 + 2*hd + 1] = n1*inv;
  }
  __syncthreads();
  // Phase C: combine (outC overlays qq)
  int e0 = tid*2;
  float wc0[16], wc1[16];
  size_t wb = (size_t)l*EE*16;
  #pragma unroll
  for (int q4=0;q4<4;++q4){
    float4 a = ldg4(Wc,f, wb + (size_t)e0*16     + q4*4);
    float4 bq = ldg4(Wc,f, wb + (size_t)(e0+1)*16 + q4*4);
    wc0[q4*4+0]=a.x; wc0[q4*4+1]=a.y; wc0[q4*4+2]=a.z; wc0[q4*4+3]=a.w;
    wc1[q4*4+0]=bq.x; wc1[q4*4+1]=bq.y; wc1[q4*4+2]=bq.z; wc1[q4*4+3]=bq.w;
  }
  float gl0=1.f,bl0=0.f,gl1=1.f,bl1=0.f;
  if (lazy){
    size_t gb = (size_t)(l-1)*EE;
    gl0 = ldg(g2v,f,gb+e0);   bl0 = ldg(b2v,f,gb+e0);
    gl1 = ldg(g2v,f,gb+e0+1); bl1 = ldg(b2v,f,gb+e0+1);
  }
  for (int t=0; t<32; ++t){
    float2 hr = *(const float2*)&hw[(size_t)(tok0+t)*EE + e0];
    float v0 = hr.x, v1 = hr.y;
    if (lazy){
      float m = msK[(grp*32+t)*2], rs = msK[(grp*32+t)*2+1];
      v0 = fmaf((v0-m)*rs, gl0, bl0);
      v1 = fmaf((v1-m)*rs, gl1, bl1);
    }
    float s0 = v0, s1 = v1;
    #pragma unroll
    for (int q4=0;q4<4;++q4){
      float4 av = *(const float4*)&AFR[t*16 + q4*4];
      s0 = fmaf(av.x, wc0[q4*4+0], fmaf(av.y, wc0[q4*4+1], fmaf(av.z, wc0[q4*4+2], fmaf(av.w, wc0[q4*4+3], s0))));
      s1 = fmaf(av.x, wc1[q4*4+0], fmaf(av.y, wc1[q4*4+1], fmaf(av.z, wc1[q4*4+2], fmaf(av.w, wc1[q4*4+3], s1))));
    }
    outC[t*520 + e0] = s0; outC[t*520 + e0 + 1] = s1;
  }
  __syncthreads();
  { // eager LN1 stats
    int token = tid>>3, prt = tid&7;
    float s=0.f, s2=0.f;
    #pragma unroll 8
    for (int i2=0;i2<64;++i2){
      float vv = outC[token*520 + prt + 8*i2];
      s += vv; s2 = fmaf(vv,vv,s2);
    }
    #pragma unroll
    for (int off=4; off; off>>=1){ s += __shfl_down(s,off,8); s2 += __shfl_down(s2,off,8); }
    if (prt==0){
      float m = s*(1.f/512.f);
      float var = s2*(1.f/512.f) - m*m;
      MS[token] = m; RS[token] = rsqrtf(var+1e-5f);
    }
  }
  __syncthreads();
  for (int u=tid; u<32*128; u+=256){
    int tok = u>>7, c4 = (u&127)*4;
    float4 vv = *(const float4*)&outC[tok*520 + c4];
    float m = MS[tok], rs = RS[tok];
    float4 gv = ldg4(g1v,f,(size_t)l*EE + c4);
    float4 bv = ldg4(b1v,f,(size_t)l*EE + c4);
    float4 o;
    o.x = fmaf((vv.x-m)*rs, gv.x, bv.x);
    o.y = fmaf((vv.y-m)*rs, gv.y, bv.y);
    o.z = fmaf((vv.z-m)*rs, gv.z, bv.z);
    o.w = fmaf((vv.w-m)*rs, gv.w, bv.w);
    if (c4 >= 16){
      *(float4*)&hw[(size_t)(tok0+tok)*EE + c4] = o;
    } else {
      *(float4*)&h16[(size_t)(tok0+tok)*16 + c4] = o;
      float4 qo;
      qo.x=__cosf(o.x); qo.y=__cosf(o.y); qo.z=__cosf(o.z); qo.w=__cosf(o.w);
      *(float4*)&qf[(size_t)(tok0+tok)*16 + c4] = qo;
    }
  }
}

// ===== FFN v4: BM=64, BN=128, BK=64, grid (128,4), 256 thr.
// Swapped GEMM1 (b64 Hc writes), double-buffered W2t+Hc, ONE barrier/iter.
__global__ __launch_bounds__(256) void ffn4_k(float* __restrict__ hw,
    const float* __restrict__ h16, const float* __restrict__ qf,
    const u16* __restrict__ W1p, const void* __restrict__ W2,
    const u16* __restrict__ W2p, float* __restrict__ st,
    const int* __restrict__ flag, int cv, int l){
  __shared__ float SMF[12288];     // 48 KiB
  u16* W2t = (u16*)SMF;            // 2 bufs x 16 slots x 512 u16
  u16* HtA = (u16*)SMF + 16384;    // 2 bufs x 8 slots x 512 u16
  float* outL = SMF;               // overlay [64][132]

  int f = *flag;
  int tid = threadIdx.x, w = tid>>6, lane = tid&63;
  int quad = lane>>4, col = lane&15;
  int mb = blockIdx.x, nb = blockIdx.y;
  int tok0 = mb*64;
  int wm = w&1, wn = w>>1;

  short8 a0[4];
  #pragma unroll
  for (int mt=0; mt<4; ++mt){
    short8 z = {0,0,0,0,0,0,0,0};
    if (quad < 2){
      const float* qp = qf + (size_t)(tok0 + mt*16 + col)*16 + quad*8;
      float4 A = *(const float4*)qp, B = *(const float4*)(qp+4);
      z[0]=(short)f2bf(A.x); z[1]=(short)f2bf(A.y); z[2]=(short)f2bf(A.z); z[3]=(short)f2bf(A.w);
      z[4]=(short)f2bf(B.x); z[5]=(short)f2bf(B.y); z[6]=(short)f2bf(B.z); z[7]=(short)f2bf(B.w);
    }
    a0[mt] = z;
  }

  f32x4 acc[2][4];
  #pragma unroll
  for (int i=0;i<2;++i)
    #pragma unroll
    for (int j=0;j<4;++j) acc[i][j] = (f32x4){0.f,0.f,0.f,0.f};
  const f32x4 zc = {0.f,0.f,0.f,0.f};
  size_t w2base = (size_t)l*EE*FF;

  auto stage = [&](int k0, int buf){
    if (cv){
      #pragma unroll
      for (int fi=0; fi<4; ++fi){
        int slot = w*4+fi, te = slot>>1, s = slot&1;
        int kb = (k0>>5) + s;
        const u16* gp = W2p + (((size_t)l*32 + nb*8 + te)*64 + kb)*512 + lane*8;
        async16(gp, &W2t[buf*8192 + slot*512 + lane*8]);
      }
    } else {
      #pragma unroll
      for (int fi=0; fi<4; ++fi){
        int slot = w*4+fi, te = slot>>1, s = slot&1;
        short8 v = ldfrag8(W2, f, w2base + (size_t)(nb*128 + te*16 + col)*FF + k0 + s*32 + quad*8);
        *(short8*)&W2t[buf*8192 + slot*512 + lane*8] = v;
      }
    }
  };
  auto gemm1 = [&](int k0, int buf){
    short8 b1 = {0,0,0,0,0,0,0,0};
    if (quad < 2)
      b1 = *(const short8*)(W1p + (((size_t)l*128 + (k0>>4) + w)*32 + quad*16 + col)*8);
    int kl = w*16 + quad*4;
    int s  = kl>>5, q2 = (kl&31)>>3, j0 = kl&7;
    u16* dst0 = &HtA[buf*4096 + s*512 + (q2*16+col)*8 + j0];
    #pragma unroll
    for (int mt=0; mt<4; ++mt){
      f32x4 hc = __builtin_amdgcn_mfma_f32_16x16x32_bf16(b1, a0[mt], zc, 0,0,0);
      ushort4 pk;
      pk.x = f2bf(fmaxf(hc[0],0.f)); pk.y = f2bf(fmaxf(hc[1],0.f));
      pk.z = f2bf(fmaxf(hc[2],0.f)); pk.w = f2bf(fmaxf(hc[3],0.f));
      *(ushort4*)(dst0 + mt*1024) = pk;    // slot (mt*2+s)*512
    }
  };

  stage(0, 0); gemm1(0, 0);
  for (int i=0; i<32; ++i){
    __syncthreads();
    int k1 = (i+1)*64;
    if (k1 < FF){ stage(k1, (i+1)&1); gemm1(k1, (i+1)&1); }
    int cb = i&1;
    #pragma unroll
    for (int s=0;s<2;++s){
      short8 A2[2], B2[4];
      A2[0] = *(const short8*)&HtA[cb*4096 + ((wm*2+0)*2+s)*512 + lane*8];
      A2[1] = *(const short8*)&HtA[cb*4096 + ((wm*2+1)*2+s)*512 + lane*8];
      #pragma unroll
      for (int et=0;et<4;++et)
        B2[et] = *(const short8*)&W2t[cb*8192 + ((wn*4+et)*2+s)*512 + lane*8];
      #pragma unroll
      for (int et=0;et<4;++et){
        acc[0][et] = __builtin_amdgcn_mfma_f32_16x16x32_bf16(A2[0], B2[et], acc[0][et], 0,0,0);
        acc[1][et] = __builtin_amdgcn_mfma_f32_16x16x32_bf16(A2[1], B2[et], acc[1][et], 0,0,0);
      }
    }
  }
  __syncthreads();

  // epilogue: pre2 = acc + residual (h16 for dims<16), partial LN stats, write
  #pragma unroll
  for (int mt2=0; mt2<2; ++mt2){
    #pragma unroll
    for (int r=0;r<4;++r){
      int ltok = wm*32 + mt2*16 + quad*4 + r;
      size_t hb = (size_t)(tok0+ltok)*EE + nb*128;
      #pragma unroll
      for (int et=0;et<4;++et){
        int eloc = wn*64 + et*16 + col;
        int eg = nb*128 + eloc;
        float rsd = (eg < 16) ? h16[(size_t)(tok0+ltok)*16 + eg] : hw[hb + eloc];
        outL[ltok*132 + eloc] = acc[mt2][et][r] + rsd;
      }
    }
  }
  __syncthreads();
  {
    int token = tid>>2, prt = tid&3;
    float s=0.f, s2=0.f;
    #pragma unroll 8
    for (int i2=0;i2<32;++i2){
      float vv = outL[token*132 + prt + 4*i2];
      s += vv; s2 = fmaf(vv,vv,s2);
    }
    s += __shfl_down(s,2,4); s2 += __shfl_down(s2,2,4);
    s += __shfl_down(s,1,4); s2 += __shfl_down(s2,1,4);
    if (prt==0){
      float2 o; o.x = s; o.y = s2;
      *(float2*)&st[((size_t)(tok0+token)*4 + nb)*2] = o;
    }
  }
  for (int u=tid; u<64*32; u+=256){
    int tok = u>>5, c4 = (u&31)*4;
    float4 vv = *(const float4*)&outL[tok*132 + c4];
    *(float4*)&hw[(size_t)(tok0+tok)*EE + nb*128 + c4] = vv;
  }
}

__global__ __launch_bounds__(256) void conv2_k(const float* __restrict__ hw,
    const float* __restrict__ st, const void* __restrict__ g2v,
    const void* __restrict__ b2v, void* __restrict__ out,
    const int* __restrict__ flag){
  int f = *flag;
  size_t i = (size_t)blockIdx.x*256 + threadIdx.x;   // float4 index
  int tok = (int)(i>>7), c4 = ((int)i&127)*4;
  float4 v = *(const float4*)&hw[i*4];
  float m, rs; tok_stats(st, tok, m, rs);
  float4 gv = ldg4(g2v,f,(size_t)3*EE + c4);
  float4 bv = ldg4(b2v,f,(size_t)3*EE + c4);
  float4 o;
  o.x = fmaf((v.x-m)*rs, gv.x, bv.x);
  o.y = fmaf((v.y-m)*rs, gv.y, bv.y);
  o.z = fmaf((v.z-m)*rs, gv.z, bv.z);
  o.w = fmaf((v.w-m)*rs, gv.w, bv.w);
  if (f){
    *(float4*)((float*)out + i*4) = o;
  } else {
    ushort4 ob; ob.x=f2bf(o.x); ob.y=f2bf(o.y); ob.z=f2bf(o.z); ob.w=f2bf(o.w);
    *(ushort4*)((u16*)out + i*4) = ob;
  }
}

extern "C" void kernel_launch(void* const* d_in, const int* in_sizes, int n_in,
                              void* d_out, int out_size, void* d_ws, size_t ws_size,
                              hipStream_t stream) {
  (void)in_sizes; (void)n_in; (void)out_size;
  char* ws = (char*)d_ws;
  int*   flag = (int*)(ws + FLAG_OFF);
  float* h16  = (float*)(ws + H16_OFF);
  float* qf   = (float*)(ws + QF_OFF);
  u16*   w1p  = (u16*)(ws + W1P_OFF);
  float* st   = (float*)(ws + STATS_OFF);
  float* hw   = (float*)(ws + H_OFF);
  u16*   w2p  = (u16*)(ws + W2P_OFF);
  int cv = (ws_size >= (size_t)W2P_OFF + ((size_t)8<<20)) ? 1 : 0;

  detect_k<<<1,256,0,stream>>>((const u16*)d_in[0], flag);
  w1pack_k<<<64,256,0,stream>>>(d_in[5], d_in[3], w1p, flag);
  if (cv) w2pack_k<<<2048,256,0,stream>>>(d_in[6], w2p, flag);
  add_pe_k<<<4096,256,0,stream>>>(d_in[0], d_in[1], hw, flag);
  for (int l=0; l<4; ++l){
    int lazy = (l>0) ? 1 : 0;
    attn_comb_k<<<256,256,0,stream>>>(hw, d_in[2], d_in[4], d_in[7], d_in[8],
                                      d_in[9], d_in[10], st, h16, qf,
                                      flag, lazy, l);
    ffn4_k<<<dim3(128,4),256,0,stream>>>(hw, h16, qf, w1p, d_in[6], w2p,
                                         st, flag, cv, l);
  }
  conv2_k<<<4096,256,0,stream>>>(hw, st, d_in[9], d_in[10], d_out, flag);
}

// Round 7
// 399.557 us; speedup vs baseline: 1.1221x; 1.1221x over previous
//
#include <hip/hip_runtime.h>
#include <cstdint>
#include <cstddef>

#define BB 8
#define SS 1024
#define EE 512
#define NQB 16
#define FF 2048

typedef unsigned short u16;
typedef __attribute__((ext_vector_type(8))) short short8;
typedef __attribute__((ext_vector_type(4))) float f32x4;

// ---- ws layout (bytes). Proven budget: ws >= 18 MiB.
#define FLAG_OFF   0
#define H16_OFF    4096                    // 512 KiB (post-LN1 dims 0..15)
#define QF_OFF     528384                  // 512 KiB
#define W1P_OFF    1052672                 // 256 KiB
#define STATS_OFF  1314816                 // 256 KiB
#define H_OFF      2097152                 // 16 MiB (ends at 18 MiB)
#define W2P_OFF    18874368                // 8 MiB, only if ws >= 26 MiB

__device__ __forceinline__ float u2f(u16 u){ return __uint_as_float(((unsigned)u)<<16); }
__device__ __forceinline__ u16 f2bf(float x){
  unsigned u = __float_as_uint(x);
  u += 0x7FFF + ((u>>16)&1);   // RNE
  return (u16)(u>>16);
}
__device__ __forceinline__ float ldg(const void* p,int f,size_t i){
  return f ? ((const float*)p)[i] : u2f(((const u16*)p)[i]);
}
__device__ __forceinline__ float4 ldg4(const void* p,int f,size_t i){ // i mult of 4
  float4 r;
  if (f){ r = ((const float4*)p)[i>>2]; }
  else { ushort4 v = ((const ushort4*)p)[i>>2];
         r.x=u2f(v.x); r.y=u2f(v.y); r.z=u2f(v.z); r.w=u2f(v.w); }
  return r;
}
__device__ __forceinline__ short8 ldfrag8(const void* p,int f,size_t i){ // i mult of 8
  short8 r;
  if (f){
    float4 A  = ((const float4*)p)[i>>2];
    float4 Bv = ((const float4*)p)[(i>>2)+1];
    r[0]=(short)f2bf(A.x);  r[1]=(short)f2bf(A.y);  r[2]=(short)f2bf(A.z);  r[3]=(short)f2bf(A.w);
    r[4]=(short)f2bf(Bv.x); r[5]=(short)f2bf(Bv.y); r[6]=(short)f2bf(Bv.z); r[7]=(short)f2bf(Bv.w);
  } else {
    r = *(const short8*)((const u16*)p + i);
  }
  return r;
}
__device__ __forceinline__ void tok_stats(const float* st, int tok, float& m, float& rs){
  float S1 = 0.f, S2 = 0.f;
  #pragma unroll
  for (int nb=0; nb<4; ++nb){
    float2 p = *(const float2*)&st[((size_t)tok*4+nb)*2];
    S1 += p.x; S2 += p.y;
  }
  m = S1*(1.f/512.f);
  float var = S2*(1.f/512.f) - m*m;
  rs = rsqrtf(var + 1e-5f);
}

__global__ void detect_k(const u16* __restrict__ x, int* __restrict__ flag){
  __shared__ int cnt;
  if (threadIdx.x==0) cnt=0;
  __syncthreads();
  int c=0;
  for (int i=threadIdx.x;i<4096;i+=256){
    u16 v = x[(size_t)i*2];
    int ex = (v>>7)&0xFF;
    c += (ex>=160) ? 1 : 0;
  }
  atomicAdd(&cnt,c);
  __syncthreads();
  if (threadIdx.x==0) *flag = (cnt>64) ? 1 : 0;
}

__global__ __launch_bounds__(256) void w1pack_k(const void* __restrict__ W1,
    const void* __restrict__ thf, u16* __restrict__ W1p, const int* __restrict__ flag){
  int f = *flag;
  int idx = blockIdx.x*256 + threadIdx.x;        // 0..16383
  int l = idx>>12, nt = (idx>>5)&127, lane32 = idx&31;
  int quad = lane32>>4, col = lane32&15;
  short8 v = ldfrag8(W1, f, ((size_t)l*FF + nt*16 + col)*16 + quad*8);
  short8 o;
  #pragma unroll
  for (int j=0;j<8;++j){
    float th = ldg(thf, f, (size_t)l*16 + quad*8 + j);
    o[j] = (short)f2bf(__cosf(th) * u2f((u16)v[j]));
  }
  *(short8*)(W1p + (size_t)idx*8) = o;
}

__global__ __launch_bounds__(256) void w2pack_k(const void* __restrict__ W2,
    u16* __restrict__ W2p, const int* __restrict__ flag){
  int f = *flag;
  int idx = blockIdx.x*256 + threadIdx.x;        // 0..524287
  int lane = idx&63, kb = (idx>>6)&63, teg = (idx>>12)&31, l = idx>>17;
  int quad = lane>>4, col = lane&15;
  short8 v = ldfrag8(W2, f, ((size_t)l*EE + teg*16 + col)*FF + kb*32 + quad*8);
  *(short8*)(W2p + (size_t)idx*8) = v;
}

__global__ __launch_bounds__(256) void add_pe_k(const void* __restrict__ x,
    const void* __restrict__ pe, float* __restrict__ hw, const int* __restrict__ flag){
  int f = *flag;
  size_t e = ((size_t)blockIdx.x*256 + threadIdx.x)*4;
  float4 xv = ldg4(x,f,e);
  float4 pv = ldg4(pe,f,e & (size_t)(SS*EE-1));
  float4 o; o.x=xv.x+pv.x; o.y=xv.y+pv.y; o.z=xv.z+pv.z; o.w=xv.w+pv.w;
  *(float4*)&hw[e] = o;
}

// ===== fused attention + combine + LN1, v5: 512 threads, key-transposed qq,
// 2-way key split, 4-key unrolled softmax with dual accumulators.
__global__ __launch_bounds__(512) void attn_comb_k(float* __restrict__ hw,
    const void* __restrict__ thA, const void* __restrict__ Wc,
    const void* __restrict__ g1v, const void* __restrict__ b1v,
    const void* __restrict__ g2v, const void* __restrict__ b2v,
    const float* __restrict__ st, float* __restrict__ h16,
    float* __restrict__ qf, const int* __restrict__ flag, int lazy, int l){
  __shared__ float SM2[20544];
  float* qq2  = SM2;             // [8][1024][2]  (phases A/B)
  float* part = SM2 + 16384;     // [32][8][2][3]
  float* msK  = SM2 + 17920;     // [1024][2]
  float* AFR  = SM2 + 19968;     // [32][16]
  float* MS   = SM2 + 20480;     // [32]
  float* RS   = SM2 + 20512;     // [32]
  float* outC = SM2;             // overlay [32][520] (phase C)
  int f = *flag;
  int tid = threadIdx.x;
  int b = blockIdx.x>>5, grp = blockIdx.x&31;
  size_t bbase = (size_t)b*SS*EE;
  int tok0 = b*SS + grp*32;

  if (lazy){
    #pragma unroll
    for (int t2=0;t2<2;++t2){
      int j = tid*2+t2;
      float m, rs; tok_stats(st, b*SS+j, m, rs);
      msK[j*2]=m; msK[j*2+1]=rs;
    }
  }
  __syncthreads();
  { // Phase A: 4 threads per token, 4 dims each; 8 passes
    int jl = tid>>2, d0 = (tid&3)*4;
    int h0 = d0>>1;
    float ct[4], gl2[4]={1,1,1,1}, bl2[4]={0,0,0,0};
    #pragma unroll
    for (int d=0;d<4;++d) ct[d] = __cosf(ldg(thA,f,(size_t)l*16+d0+d));
    if (lazy){
      float4 gv = ldg4(g2v,f,(size_t)(l-1)*EE+d0);
      float4 bv = ldg4(b2v,f,(size_t)(l-1)*EE+d0);
      gl2[0]=gv.x; gl2[1]=gv.y; gl2[2]=gv.z; gl2[3]=gv.w;
      bl2[0]=bv.x; bl2[1]=bv.y; bl2[2]=bv.z; bl2[3]=bv.w;
    }
    #pragma unroll 2
    for (int it=0; it<8; ++it){
      int j = jl + it*128;
      float4 hv = *(const float4*)&hw[bbase + (size_t)j*EE + d0];
      float vv[4] = {hv.x, hv.y, hv.z, hv.w};
      if (lazy){
        float m = msK[j*2], rs = msK[j*2+1];
        #pragma unroll
        for (int d=0;d<4;++d) vv[d] = fmaf((vv[d]-m)*rs, gl2[d], bl2[d]);
      }
      float2 o0, o1;
      o0.x = ct[0]*__cosf(vv[0]); o0.y = ct[1]*__cosf(vv[1]);
      o1.x = ct[2]*__cosf(vv[2]); o1.y = ct[3]*__cosf(vv[3]);
      *(float2*)&qq2[h0*2048 + j*2]     = o0;
      *(float2*)&qq2[(h0+1)*2048 + j*2] = o1;
    }
  }
  __syncthreads();
  { // Phase B: thread = (row 32, head 8, kz 2); 512 keys each, 4-key unroll
    int r = tid&31, hd = (tid>>5)&7, kz = tid>>8;
    int rg = grp*32 + r;
    const float* qh = &qq2[hd*2048];
    float a0 = qh[rg*2], a1 = qh[rg*2+1];
    const float sc = 0.70710678118f;
    float a0s = a0*sc, a1s = a1*sc;
    float dA=0.f, x0A=0.f, x1A=0.f, dB=0.f, x0B=0.f, x1B=0.f;
    const float* qp = qh + kz*1024;
    for (int j=0; j<512; j+=4){
      float4 P = *(const float4*)(qp + j*2);
      float4 Q = *(const float4*)(qp + j*2 + 4);
      float e0 = __expf(fmaf(a1s,P.y, a0s*P.x));
      float e1 = __expf(fmaf(a1s,P.w, a0s*P.z));
      float e2 = __expf(fmaf(a1s,Q.y, a0s*Q.x));
      float e3 = __expf(fmaf(a1s,Q.w, a0s*Q.z));
      dA += e0; x0A = fmaf(e0,P.x,x0A); x1A = fmaf(e0,P.y,x1A);
      dB += e1; x0B = fmaf(e1,P.z,x0B); x1B = fmaf(e1,P.w,x1B);
      dA += e2; x0A = fmaf(e2,Q.x,x0A); x1A = fmaf(e2,Q.y,x1A);
      dB += e3; x0B = fmaf(e3,Q.z,x0B); x1B = fmaf(e3,Q.w,x1B);
    }
    float* pp = &part[((r*8+hd)*2+kz)*3];
    pp[0]=dA+dB; pp[1]=x0A+x0B; pp[2]=x1A+x1B;
  }
  __syncthreads();
  if (tid < 256){
    int r = tid&31, hd = tid>>5;
    const float* p0 = &part[((r*8+hd)*2+0)*3];
    const float* p1 = &part[((r*8+hd)*2+1)*3];
    float d = p0[0]+p1[0];
    float inv = 1.f/d;
    AFR[r*16 + 2*hd]   = (p0[1]+p1[1])*inv;
    AFR[r*16 + 2*hd+1] = (p0[2]+p1[2])*inv;
  }
  __syncthreads();
  // Phase C: combine, 1 col/thread (outC overlays qq2/part; AFR/msK safe)
  {
    int e0 = tid;
    float wc[16];
    size_t wb = (size_t)l*EE*16 + (size_t)e0*16;
    #pragma unroll
    for (int q4=0;q4<4;++q4){
      float4 a = ldg4(Wc,f, wb + q4*4);
      wc[q4*4+0]=a.x; wc[q4*4+1]=a.y; wc[q4*4+2]=a.z; wc[q4*4+3]=a.w;
    }
    float gl0=1.f,bl0=0.f;
    if (lazy){
      gl0 = ldg(g2v,f,(size_t)(l-1)*EE+e0);
      bl0 = ldg(b2v,f,(size_t)(l-1)*EE+e0);
    }
    for (int t=0; t<32; ++t){
      float v0 = hw[(size_t)(tok0+t)*EE + e0];
      if (lazy){
        float m = msK[(grp*32+t)*2], rs = msK[(grp*32+t)*2+1];
        v0 = fmaf((v0-m)*rs, gl0, bl0);
      }
      float s0 = v0;
      #pragma unroll
      for (int q4=0;q4<4;++q4){
        float4 av = *(const float4*)&AFR[t*16 + q4*4];
        s0 = fmaf(av.x, wc[q4*4+0], fmaf(av.y, wc[q4*4+1], fmaf(av.z, wc[q4*4+2], fmaf(av.w, wc[q4*4+3], s0))));
      }
      outC[t*520 + e0] = s0;
    }
  }
  __syncthreads();
  { // eager LN1 stats: 16 threads per token
    int token = tid>>4, prt = tid&15;
    float s=0.f, s2=0.f;
    #pragma unroll 8
    for (int i2=0;i2<32;++i2){
      float vv = outC[token*520 + prt + 16*i2];
      s += vv; s2 = fmaf(vv,vv,s2);
    }
    #pragma unroll
    for (int off=8; off; off>>=1){ s += __shfl_down(s,off,16); s2 += __shfl_down(s2,off,16); }
    if (prt==0){
      float m = s*(1.f/512.f);
      float var = s2*(1.f/512.f) - m*m;
      MS[token] = m; RS[token] = rsqrtf(var+1e-5f);
    }
  }
  __syncthreads();
  for (int u=tid; u<32*128; u+=512){
    int tok = u>>7, c4 = (u&127)*4;
    float4 vv = *(const float4*)&outC[tok*520 + c4];
    float m = MS[tok], rs = RS[tok];
    float4 gv = ldg4(g1v,f,(size_t)l*EE + c4);
    float4 bv = ldg4(b1v,f,(size_t)l*EE + c4);
    float4 o;
    o.x = fmaf((vv.x-m)*rs, gv.x, bv.x);
    o.y = fmaf((vv.y-m)*rs, gv.y, bv.y);
    o.z = fmaf((vv.z-m)*rs, gv.z, bv.z);
    o.w = fmaf((vv.w-m)*rs, gv.w, bv.w);
    if (c4 >= 16){
      *(float4*)&hw[(size_t)(tok0+tok)*EE + c4] = o;
    } else {
      *(float4*)&h16[(size_t)(tok0+tok)*16 + c4] = o;
      float4 qo;
      qo.x=__cosf(o.x); qo.y=__cosf(o.y); qo.z=__cosf(o.z); qo.w=__cosf(o.w);
      *(float4*)&qf[(size_t)(tok0+tok)*16 + c4] = qo;
    }
  }
}

// ===== FFN v5: BM=64, BN=128, BK=64, grid (128,4), 256 thr. Wave-tile M64xN32.
// No W2 LDS staging: B-frags direct global->VGPR (packed frag-major, L2-res),
// 2-deep register prefetch for B2 and W1p. Hc double-buffered, ONE barrier/iter.
__global__ __launch_bounds__(256) void ffn5_k(float* __restrict__ hw,
    const float* __restrict__ h16, const float* __restrict__ qf,
    const u16* __restrict__ W1p, const void* __restrict__ W2,
    const u16* __restrict__ W2p, float* __restrict__ st,
    const int* __restrict__ flag, int cv, int l){
  __shared__ float SMF[8448];      // 33 KiB
  u16* HtA = (u16*)SMF;            // 2 bufs x 8 slots x 512 u16 = 16 KiB
  float* outL = SMF;               // overlay [64][132]

  int f = *flag;
  int tid = threadIdx.x, w = tid>>6, lane = tid&63;
  int quad = lane>>4, col = lane&15;
  int mb = blockIdx.x, nb = blockIdx.y;
  int tok0 = mb*64;

  short8 a0[4];
  #pragma unroll
  for (int mt=0; mt<4; ++mt){
    short8 z = {0,0,0,0,0,0,0,0};
    if (quad < 2){
      const float* qp = qf + (size_t)(tok0 + mt*16 + col)*16 + quad*8;
      float4 A = *(const float4*)qp, B = *(const float4*)(qp+4);
      z[0]=(short)f2bf(A.x); z[1]=(short)f2bf(A.y); z[2]=(short)f2bf(A.z); z[3]=(short)f2bf(A.w);
      z[4]=(short)f2bf(B.x); z[5]=(short)f2bf(B.y); z[6]=(short)f2bf(B.z); z[7]=(short)f2bf(B.w);
    }
    a0[mt] = z;
  }

  f32x4 acc[4][2];
  #pragma unroll
  for (int i=0;i<4;++i){ acc[i][0]=(f32x4){0,0,0,0}; acc[i][1]=(f32x4){0,0,0,0}; }
  const f32x4 zc = {0.f,0.f,0.f,0.f};
  size_t w2base = (size_t)l*EE*FF;

  // W1 frag loader (k0 in elements)
  auto loadW1 = [&](int k0)->short8{
    short8 z = {0,0,0,0,0,0,0,0};
    if (quad < 2)
      z = *(const short8*)(W1p + (((size_t)l*128 + (k0>>4) + w)*32 + quad*16 + col)*8);
    return z;
  };
  // B2 frag loader into B[2][2]
  auto loadB2 = [&](short8 (&B)[2][2], int k0){
    if (cv){
      #pragma unroll
      for (int et=0;et<2;++et)
        #pragma unroll
        for (int s=0;s<2;++s)
          B[et][s] = *(const short8*)(W2p + ((((size_t)l*32 + nb*8 + w*2 + et)*64)
                       + (k0>>5) + s)*512 + lane*8);
    } else {
      #pragma unroll
      for (int et=0;et<2;++et)
        #pragma unroll
        for (int s=0;s<2;++s)
          B[et][s] = ldfrag8(W2, f, w2base
                       + (size_t)(nb*128 + w*32 + et*16 + col)*FF + k0 + s*32 + quad*8);
    }
  };
  auto gemm1 = [&](int buf, short8 b1){
    int kl = w*16 + quad*4;
    int s  = kl>>5, q2 = (kl&31)>>3, j0 = kl&7;
    u16* dst0 = &HtA[buf*4096 + s*512 + (q2*16+col)*8 + j0];
    #pragma unroll
    for (int mt=0; mt<4; ++mt){
      f32x4 hc = __builtin_amdgcn_mfma_f32_16x16x32_bf16(b1, a0[mt], zc, 0,0,0);
      ushort4 pk;
      pk.x = f2bf(fmaxf(hc[0],0.f)); pk.y = f2bf(fmaxf(hc[1],0.f));
      pk.z = f2bf(fmaxf(hc[2],0.f)); pk.w = f2bf(fmaxf(hc[3],0.f));
      *(ushort4*)(dst0 + mt*1024) = pk;    // slot (mt*2+s)*512
    }
  };

  short8 B2c[2][2], B2n[2][2];
  short8 b1n;
  {
    short8 b1 = loadW1(0);
    loadB2(B2c, 0);
    gemm1(0, b1);
    b1n = loadW1(64);
  }
  __syncthreads();
  for (int i=0; i<32; ++i){
    if (i < 31){
      loadB2(B2n, (i+1)*64);
      gemm1((i+1)&1, b1n);
      int k2 = (i+2 < 32) ? (i+2)*64 : 0;
      b1n = loadW1(k2);
    }
    int cb = i&1;
    #pragma unroll
    for (int s=0;s<2;++s){
      short8 A2[4];
      #pragma unroll
      for (int mt=0;mt<4;++mt)
        A2[mt] = *(const short8*)&HtA[cb*4096 + (mt*2+s)*512 + lane*8];
      #pragma unroll
      for (int et=0;et<2;++et)
        #pragma unroll
        for (int mt=0;mt<4;++mt)
          acc[mt][et] = __builtin_amdgcn_mfma_f32_16x16x32_bf16(A2[mt], B2c[et][s], acc[mt][et], 0,0,0);
    }
    __syncthreads();
    if (i < 31){
      #pragma unroll
      for (int et=0;et<2;++et){ B2c[et][0]=B2n[et][0]; B2c[et][1]=B2n[et][1]; }
    }
  }

  // epilogue: pre2 = acc + residual; partial LN stats; write hw
  #pragma unroll
  for (int mt=0; mt<4; ++mt){
    #pragma unroll
    for (int r=0;r<4;++r){
      int ltok = mt*16 + quad*4 + r;
      size_t hb = (size_t)(tok0+ltok)*EE + nb*128;
      #pragma unroll
      for (int et=0;et<2;++et){
        int eloc = w*32 + et*16 + col;
        int eg = nb*128 + eloc;
        float rsd = (eg < 16) ? h16[(size_t)(tok0+ltok)*16 + eg] : hw[hb + eloc];
        outL[ltok*132 + eloc] = acc[mt][et][r] + rsd;
      }
    }
  }
  __syncthreads();
  {
    int token = tid>>2, prt = tid&3;
    float s=0.f, s2=0.f;
    #pragma unroll 8
    for (int i2=0;i2<32;++i2){
      float vv = outL[token*132 + prt + 4*i2];
      s += vv; s2 = fmaf(vv,vv,s2);
    }
    s += __shfl_down(s,2,4); s2 += __shfl_down(s2,2,4);
    s += __shfl_down(s,1,4); s2 += __shfl_down(s2,1,4);
    if (prt==0){
      float2 o; o.x = s; o.y = s2;
      *(float2*)&st[((size_t)(tok0+token)*4 + nb)*2] = o;
    }
  }
  for (int u=tid; u<64*32; u+=256){
    int tok = u>>5, c4 = (u&31)*4;
    float4 vv = *(const float4*)&outL[tok*132 + c4];
    *(float4*)&hw[(size_t)(tok0+tok)*EE + nb*128 + c4] = vv;
  }
}

__global__ __launch_bounds__(256) void conv2_k(const float* __restrict__ hw,
    const float* __restrict__ st, const void* __restrict__ g2v,
    const void* __restrict__ b2v, void* __restrict__ out,
    const int* __restrict__ flag){
  int f = *flag;
  size_t i = (size_t)blockIdx.x*256 + threadIdx.x;   // float4 index
  int tok = (int)(i>>7), c4 = ((int)i&127)*4;
  float4 v = *(const float4*)&hw[i*4];
  float m, rs; tok_stats(st, tok, m, rs);
  float4 gv = ldg4(g2v,f,(size_t)3*EE + c4);
  float4 bv = ldg4(b2v,f,(size_t)3*EE + c4);
  float4 o;
  o.x = fmaf((v.x-m)*rs, gv.x, bv.x);
  o.y = fmaf((v.y-m)*rs, gv.y, bv.y);
  o.z = fmaf((v.z-m)*rs, gv.z, bv.z);
  o.w = fmaf((v.w-m)*rs, gv.w, bv.w);
  if (f){
    *(float4*)((float*)out + i*4) = o;
  } else {
    ushort4 ob; ob.x=f2bf(o.x); ob.y=f2bf(o.y); ob.z=f2bf(o.z); ob.w=f2bf(o.w);
    *(ushort4*)((u16*)out + i*4) = ob;
  }
}

extern "C" void kernel_launch(void* const* d_in, const int* in_sizes, int n_in,
                              void* d_out, int out_size, void* d_ws, size_t ws_size,
                              hipStream_t stream) {
  (void)in_sizes; (void)n_in; (void)out_size;
  char* ws = (char*)d_ws;
  int*   flag = (int*)(ws + FLAG_OFF);
  float* h16  = (float*)(ws + H16_OFF);
  float* qf   = (float*)(ws + QF_OFF);
  u16*   w1p  = (u16*)(ws + W1P_OFF);
  float* st   = (float*)(ws + STATS_OFF);
  float* hw   = (float*)(ws + H_OFF);
  u16*   w2p  = (u16*)(ws + W2P_OFF);
  int cv = (ws_size >= (size_t)W2P_OFF + ((size_t)8<<20)) ? 1 : 0;

  detect_k<<<1,256,0,stream>>>((const u16*)d_in[0], flag);
  w1pack_k<<<64,256,0,stream>>>(d_in[5], d_in[3], w1p, flag);
  if (cv) w2pack_k<<<2048,256,0,stream>>>(d_in[6], w2p, flag);
  add_pe_k<<<4096,256,0,stream>>>(d_in[0], d_in[1], hw, flag);
  for (int l=0; l<4; ++l){
    int lazy = (l>0) ? 1 : 0;
    attn_comb_k<<<256,512,0,stream>>>(hw, d_in[2], d_in[4], d_in[7], d_in[8],
                                      d_in[9], d_in[10], st, h16, qf,
                                      flag, lazy, l);
    ffn5_k<<<dim3(128,4),256,0,stream>>>(hw, h16, qf, w1p, d_in[6], w2p,
                                         st, flag, cv, l);
  }
  conv2_k<<<4096,256,0,stream>>>(hw, st, d_in[9], d_in[10], d_out, flag);
}

// Round 8
// 369.952 us; speedup vs baseline: 1.2119x; 1.0800x over previous
//
#include <hip/hip_runtime.h>
#include <cstdint>
#include <cstddef>

#define BB 8
#define SS 1024
#define EE 512
#define NQB 16
#define FF 2048

typedef unsigned short u16;
typedef __attribute__((ext_vector_type(8))) short short8;
typedef __attribute__((ext_vector_type(4))) float f32x4;

// ---- ws layout (bytes). Proven budget: ws >= 18 MiB (cv path needs 26 MiB; ws is 256MB).
#define FLAG_OFF   0
#define H16_OFF    4096                    // 512 KiB (post-LN1 dims 0..15)
#define QF_OFF     528384                  // 512 KiB
#define W1P_OFF    1052672                 // 256 KiB
#define STATS_OFF  1314816                 // 256 KiB
#define H_OFF      2097152                 // 16 MiB (ends at 18 MiB)
#define W2P_OFF    18874368                // 8 MiB, only if ws >= 26 MiB

__device__ __forceinline__ float u2f(u16 u){ return __uint_as_float(((unsigned)u)<<16); }
__device__ __forceinline__ u16 f2bf(float x){
  unsigned u = __float_as_uint(x);
  u += 0x7FFF + ((u>>16)&1);   // RNE
  return (u16)(u>>16);
}
__device__ __forceinline__ float ldg(const void* p,int f,size_t i){
  return f ? ((const float*)p)[i] : u2f(((const u16*)p)[i]);
}
__device__ __forceinline__ float4 ldg4(const void* p,int f,size_t i){ // i mult of 4
  float4 r;
  if (f){ r = ((const float4*)p)[i>>2]; }
  else { ushort4 v = ((const ushort4*)p)[i>>2];
         r.x=u2f(v.x); r.y=u2f(v.y); r.z=u2f(v.z); r.w=u2f(v.w); }
  return r;
}
__device__ __forceinline__ short8 ldfrag8(const void* p,int f,size_t i){ // i mult of 8
  short8 r;
  if (f){
    float4 A  = ((const float4*)p)[i>>2];
    float4 Bv = ((const float4*)p)[(i>>2)+1];
    r[0]=(short)f2bf(A.x);  r[1]=(short)f2bf(A.y);  r[2]=(short)f2bf(A.z);  r[3]=(short)f2bf(A.w);
    r[4]=(short)f2bf(Bv.x); r[5]=(short)f2bf(Bv.y); r[6]=(short)f2bf(Bv.z); r[7]=(short)f2bf(Bv.w);
  } else {
    r = *(const short8*)((const u16*)p + i);
  }
  return r;
}
__device__ __forceinline__ void tok_stats(const float* st, int tok, float& m, float& rs){
  float S1 = 0.f, S2 = 0.f;
  #pragma unroll
  for (int nb=0; nb<4; ++nb){
    float2 p = *(const float2*)&st[((size_t)tok*4+nb)*2];
    S1 += p.x; S2 += p.y;
  }
  m = S1*(1.f/512.f);
  float var = S2*(1.f/512.f) - m*m;
  rs = rsqrtf(var + 1e-5f);
}

__global__ void detect_k(const u16* __restrict__ x, int* __restrict__ flag){
  __shared__ int cnt;
  if (threadIdx.x==0) cnt=0;
  __syncthreads();
  int c=0;
  for (int i=threadIdx.x;i<4096;i+=256){
    u16 v = x[(size_t)i*2];
    int ex = (v>>7)&0xFF;
    c += (ex>=160) ? 1 : 0;
  }
  atomicAdd(&cnt,c);
  __syncthreads();
  if (threadIdx.x==0) *flag = (cnt>64) ? 1 : 0;
}

__global__ __launch_bounds__(256) void w1pack_k(const void* __restrict__ W1,
    const void* __restrict__ thf, u16* __restrict__ W1p, const int* __restrict__ flag){
  int f = *flag;
  int idx = blockIdx.x*256 + threadIdx.x;        // 0..16383
  int l = idx>>12, nt = (idx>>5)&127, lane32 = idx&31;
  int quad = lane32>>4, col = lane32&15;
  short8 v = ldfrag8(W1, f, ((size_t)l*FF + nt*16 + col)*16 + quad*8);
  short8 o;
  #pragma unroll
  for (int j=0;j<8;++j){
    float th = ldg(thf, f, (size_t)l*16 + quad*8 + j);
    o[j] = (short)f2bf(__cosf(th) * u2f((u16)v[j]));
  }
  *(short8*)(W1p + (size_t)idx*8) = o;
}

__global__ __launch_bounds__(256) void w2pack_k(const void* __restrict__ W2,
    u16* __restrict__ W2p, const int* __restrict__ flag){
  int f = *flag;
  int idx = blockIdx.x*256 + threadIdx.x;        // 0..524287
  int lane = idx&63, kb = (idx>>6)&63, teg = (idx>>12)&31, l = idx>>17;
  int quad = lane>>4, col = lane&15;
  short8 v = ldfrag8(W2, f, ((size_t)l*EE + teg*16 + col)*FF + kb*32 + quad*8);
  *(short8*)(W2p + (size_t)idx*8) = v;
}

__global__ __launch_bounds__(256) void add_pe_k(const void* __restrict__ x,
    const void* __restrict__ pe, float* __restrict__ hw, const int* __restrict__ flag){
  int f = *flag;
  size_t e = ((size_t)blockIdx.x*256 + threadIdx.x)*4;
  float4 xv = ldg4(x,f,e);
  float4 pv = ldg4(pe,f,e & (size_t)(SS*EE-1));
  float4 o; o.x=xv.x+pv.x; o.y=xv.y+pv.y; o.z=xv.z+pv.z; o.w=xv.w+pv.w;
  *(float4*)&hw[e] = o;
}

// ===== fused attention + combine + LN1, v7: 512 blocks (16-token groups),
// 512 threads, 2 blocks/CU = 4 waves/SIMD. Key-transposed qq, 4-way K-split.
__global__ __launch_bounds__(512) void attn_comb_k(float* __restrict__ hw,
    const void* __restrict__ thA, const void* __restrict__ Wc,
    const void* __restrict__ g1v, const void* __restrict__ b1v,
    const void* __restrict__ g2v, const void* __restrict__ b2v,
    const float* __restrict__ st, float* __restrict__ h16,
    float* __restrict__ qf, const int* __restrict__ flag, int lazy, int l){
  __shared__ float SM2[20256];   // 81,024 B: exactly 2 blocks/CU
  float* qq2  = SM2;             // [8][1024][2] = 16384 f  (phases A/B)
  float* part = SM2 + 16384;     // [16][8][4][3] = 1536 f
  float* msK  = SM2 + 17920;     // [1024][2] = 2048 f
  float* AFR  = SM2 + 19968;     // [16][16] = 256 f
  float* MS   = SM2 + 20224;     // [16]
  float* RS   = SM2 + 20240;     // [16]
  float* outC = SM2;             // overlay [16][520] = 8320 f (phase C)
  int f = *flag;
  int tid = threadIdx.x;
  int b = blockIdx.x>>6, grp = blockIdx.x&63;
  size_t bbase = (size_t)b*SS*EE;
  int tok0 = b*SS + grp*16;

  if (lazy){
    #pragma unroll
    for (int t2=0;t2<2;++t2){
      int j = tid*2+t2;
      float m, rs; tok_stats(st, b*SS+j, m, rs);
      msK[j*2]=m; msK[j*2+1]=rs;
    }
    __syncthreads();
  }
  { // Phase A: 4 threads per token, 4 dims each; 8 passes of 128 tokens
    int jl = tid>>2, d0 = (tid&3)*4;
    int h0 = d0>>1;
    float ct[4], gl2[4]={1,1,1,1}, bl2[4]={0,0,0,0};
    #pragma unroll
    for (int d=0;d<4;++d) ct[d] = __cosf(ldg(thA,f,(size_t)l*16+d0+d));
    if (lazy){
      float4 gv = ldg4(g2v,f,(size_t)(l-1)*EE+d0);
      float4 bv = ldg4(b2v,f,(size_t)(l-1)*EE+d0);
      gl2[0]=gv.x; gl2[1]=gv.y; gl2[2]=gv.z; gl2[3]=gv.w;
      bl2[0]=bv.x; bl2[1]=bv.y; bl2[2]=bv.z; bl2[3]=bv.w;
    }
    #pragma unroll 2
    for (int it=0; it<8; ++it){
      int j = jl + it*128;
      float4 hv = *(const float4*)&hw[bbase + (size_t)j*EE + d0];
      float vv[4] = {hv.x, hv.y, hv.z, hv.w};
      if (lazy){
        float m = msK[j*2], rs = msK[j*2+1];
        #pragma unroll
        for (int d=0;d<4;++d) vv[d] = fmaf((vv[d]-m)*rs, gl2[d], bl2[d]);
      }
      float2 o0, o1;
      o0.x = ct[0]*__cosf(vv[0]); o0.y = ct[1]*__cosf(vv[1]);
      o1.x = ct[2]*__cosf(vv[2]); o1.y = ct[3]*__cosf(vv[3]);
      *(float2*)&qq2[h0*2048 + j*2]     = o0;
      *(float2*)&qq2[(h0+1)*2048 + j*2] = o1;
    }
  }
  __syncthreads();
  { // Phase B: thread = (row 16, head 8, kz 4); 256 keys each, 4-key unroll
    int r = tid&15, hd = (tid>>4)&7, kz = tid>>7;
    int rg = grp*16 + r;
    const float* qh = &qq2[hd*2048];
    float a0 = qh[rg*2], a1 = qh[rg*2+1];
    const float sc = 0.70710678118f;
    float a0s = a0*sc, a1s = a1*sc;
    float dA=0.f, x0A=0.f, x1A=0.f, dB=0.f, x0B=0.f, x1B=0.f;
    const float* qp = qh + kz*512;
    for (int j=0; j<256; j+=4){
      float4 P = *(const float4*)(qp + j*2);
      float4 Q = *(const float4*)(qp + j*2 + 4);
      float e0 = __expf(fmaf(a1s,P.y, a0s*P.x));
      float e1 = __expf(fmaf(a1s,P.w, a0s*P.z));
      float e2 = __expf(fmaf(a1s,Q.y, a0s*Q.x));
      float e3 = __expf(fmaf(a1s,Q.w, a0s*Q.z));
      dA += e0; x0A = fmaf(e0,P.x,x0A); x1A = fmaf(e0,P.y,x1A);
      dB += e1; x0B = fmaf(e1,P.z,x0B); x1B = fmaf(e1,P.w,x1B);
      dA += e2; x0A = fmaf(e2,Q.x,x0A); x1A = fmaf(e2,Q.y,x1A);
      dB += e3; x0B = fmaf(e3,Q.z,x0B); x1B = fmaf(e3,Q.w,x1B);
    }
    float* pp = &part[((r*8+hd)*4+kz)*3];
    pp[0]=dA+dB; pp[1]=x0A+x0B; pp[2]=x1A+x1B;
  }
  __syncthreads();
  if (tid < 128){
    int r = tid&15, hd = tid>>4;
    float d=0.f, s0=0.f, s1=0.f;
    #pragma unroll
    for (int k=0;k<4;++k){
      const float* pp = &part[((r*8+hd)*4+k)*3];
      d += pp[0]; s0 += pp[1]; s1 += pp[2];
    }
    float inv = 1.f/d;
    AFR[r*16 + 2*hd]   = s0*inv;
    AFR[r*16 + 2*hd+1] = s1*inv;
  }
  __syncthreads();
  // Phase C: combine, 1 col/thread over 16 tokens (outC overlays qq2)
  {
    int e0 = tid;
    float wc[16];
    size_t wb = (size_t)l*EE*16 + (size_t)e0*16;
    #pragma unroll
    for (int q4=0;q4<4;++q4){
      float4 a = ldg4(Wc,f, wb + q4*4);
      wc[q4*4+0]=a.x; wc[q4*4+1]=a.y; wc[q4*4+2]=a.z; wc[q4*4+3]=a.w;
    }
    float gl0=1.f,bl0=0.f;
    if (lazy){
      gl0 = ldg(g2v,f,(size_t)(l-1)*EE+e0);
      bl0 = ldg(b2v,f,(size_t)(l-1)*EE+e0);
    }
    #pragma unroll 4
    for (int t=0; t<16; ++t){
      float v0 = hw[(size_t)(tok0+t)*EE + e0];
      if (lazy){
        float m = msK[(grp*16+t)*2], rs = msK[(grp*16+t)*2+1];
        v0 = fmaf((v0-m)*rs, gl0, bl0);
      }
      float s0 = v0;
      #pragma unroll
      for (int q4=0;q4<4;++q4){
        float4 av = *(const float4*)&AFR[t*16 + q4*4];
        s0 = fmaf(av.x, wc[q4*4+0], fmaf(av.y, wc[q4*4+1], fmaf(av.z, wc[q4*4+2], fmaf(av.w, wc[q4*4+3], s0))));
      }
      outC[t*520 + e0] = s0;
    }
  }
  __syncthreads();
  { // eager LN1 stats: 32 threads per token
    int token = tid>>5, prt = tid&31;
    float s=0.f, s2=0.f;
    #pragma unroll 8
    for (int i2=0;i2<16;++i2){
      float vv = outC[token*520 + prt + 32*i2];
      s += vv; s2 = fmaf(vv,vv,s2);
    }
    #pragma unroll
    for (int off=16; off; off>>=1){ s += __shfl_down(s,off,32); s2 += __shfl_down(s2,off,32); }
    if (prt==0){
      float m = s*(1.f/512.f);
      float var = s2*(1.f/512.f) - m*m;
      MS[token] = m; RS[token] = rsqrtf(var+1e-5f);
    }
  }
  __syncthreads();
  for (int u=tid; u<16*128; u+=512){
    int tok = u>>7, c4 = (u&127)*4;
    float4 vv = *(const float4*)&outC[tok*520 + c4];
    float m = MS[tok], rs = RS[tok];
    float4 gv = ldg4(g1v,f,(size_t)l*EE + c4);
    float4 bv = ldg4(b1v,f,(size_t)l*EE + c4);
    float4 o;
    o.x = fmaf((vv.x-m)*rs, gv.x, bv.x);
    o.y = fmaf((vv.y-m)*rs, gv.y, bv.y);
    o.z = fmaf((vv.z-m)*rs, gv.z, bv.z);
    o.w = fmaf((vv.w-m)*rs, gv.w, bv.w);
    if (c4 >= 16){
      *(float4*)&hw[(size_t)(tok0+tok)*EE + c4] = o;
    } else {
      *(float4*)&h16[(size_t)(tok0+tok)*16 + c4] = o;
      float4 qo;
      qo.x=__cosf(o.x); qo.y=__cosf(o.y); qo.z=__cosf(o.z); qo.w=__cosf(o.w);
      *(float4*)&qf[(size_t)(tok0+tok)*16 + c4] = qo;
    }
  }
}

// ===== FFN v6: BM=64, BN=128, BK=128, grid (128,4), 256 thr. 16 barriers.
// Hc double-buffered [2][16][512] u16 (proper bounds). B2 direct global->VGPR
// (packed frag-major), prefetched one iter ahead. Each wave owns kk32-slot w.
__global__ __launch_bounds__(256) void ffn6_k(float* __restrict__ hw,
    const float* __restrict__ h16, const float* __restrict__ qf,
    const u16* __restrict__ W1p, const void* __restrict__ W2,
    const u16* __restrict__ W2p, float* __restrict__ st,
    const int* __restrict__ flag, int cv, int l){
  __shared__ float SMF[8704];      // 34,816 B
  u16* HtA = (u16*)SMF;            // [2 bufs][16 slots][512] u16 = 32,768 B
  float* outL = SMF;               // overlay [64][132] = 33,792 B

  int f = *flag;
  int tid = threadIdx.x, w = tid>>6, lane = tid&63;
  int quad = lane>>4, col = lane&15;
  int mb = blockIdx.x, nb = blockIdx.y;
  int tok0 = mb*64;

  short8 a0[4];
  #pragma unroll
  for (int mt=0; mt<4; ++mt){
    short8 z = {0,0,0,0,0,0,0,0};
    if (quad < 2){
      const float* qp = qf + (size_t)(tok0 + mt*16 + col)*16 + quad*8;
      float4 A = *(const float4*)qp, B = *(const float4*)(qp+4);
      z[0]=(short)f2bf(A.x); z[1]=(short)f2bf(A.y); z[2]=(short)f2bf(A.z); z[3]=(short)f2bf(A.w);
      z[4]=(short)f2bf(B.x); z[5]=(short)f2bf(B.y); z[6]=(short)f2bf(B.z); z[7]=(short)f2bf(B.w);
    }
    a0[mt] = z;
  }

  f32x4 acc[4][2];
  #pragma unroll
  for (int i=0;i<4;++i){ acc[i][0]=(f32x4){0,0,0,0}; acc[i][1]=(f32x4){0,0,0,0}; }
  const f32x4 zc = {0.f,0.f,0.f,0.f};
  size_t w2base = (size_t)l*EE*FF;

  // W1 frag pair for this wave's two k16-cols (2w, 2w+1) at k0
  auto loadW1 = [&](int k0, short8& A, short8& B){
    short8 z = {0,0,0,0,0,0,0,0};
    A = z; B = z;
    if (quad < 2){
      size_t base = ((size_t)l*128 + (k0>>4) + 2*w)*32 + quad*16 + col;
      A = *(const short8*)(W1p + base*8);
      B = *(const short8*)(W1p + (base+32)*8);
    }
  };
  // B2 frags [et][kk32] for this wave's 2 E-tiles at k0 (128 k)
  auto loadB2 = [&](short8 (&B)[2][4], int k0){
    if (cv){
      #pragma unroll
      for (int et=0;et<2;++et)
        #pragma unroll
        for (int kk=0;kk<4;++kk)
          B[et][kk] = *(const short8*)(W2p +
            (((size_t)l*32 + nb*8 + w*2 + et)*64 + (k0>>5) + kk)*512 + lane*8);
    } else {
      #pragma unroll
      for (int et=0;et<2;++et)
        #pragma unroll
        for (int kk=0;kk<4;++kk)
          B[et][kk] = ldfrag8(W2, f, w2base
            + (size_t)(nb*128 + (w*2+et)*16 + col)*FF + k0 + kk*32 + quad*8);
    }
  };
  // GEMM1 for chunk pair -> buf; wave owns kk32 slot = w
  auto gemm1pair = [&](int buf, short8 b1a, short8 b1b){
    #pragma unroll
    for (int cc=0; cc<2; ++cc){
      short8 b1 = cc ? b1b : b1a;
      int p = cc*16 + quad*4;
      u16* dst = &HtA[(size_t)(buf*16 + w)*512 + ((p>>3)*16 + col)*8 + (p&7)];
      #pragma unroll
      for (int mt=0; mt<4; ++mt){
        f32x4 hc = __builtin_amdgcn_mfma_f32_16x16x32_bf16(b1, a0[mt], zc, 0,0,0);
        ushort4 pk;
        pk.x = f2bf(fmaxf(hc[0],0.f)); pk.y = f2bf(fmaxf(hc[1],0.f));
        pk.z = f2bf(fmaxf(hc[2],0.f)); pk.w = f2bf(fmaxf(hc[3],0.f));
        *(ushort4*)(dst + (size_t)mt*4*512) = pk;    // slot mt*4 + w
      }
    }
  };

  short8 B2c[2][4], B2n[2][4], w1a, w1b, w1na, w1nb;
  loadB2(B2c, 0);
  loadW1(0, w1a, w1b);
  gemm1pair(0, w1a, w1b);
  loadW1(128, w1na, w1nb);
  __syncthreads();
  for (int i=0; i<16; ++i){
    if (i < 15){
      loadB2(B2n, (i+1)*128);
      gemm1pair((i+1)&1, w1na, w1nb);
      if (i < 14) loadW1((i+2)*128, w1na, w1nb);
    }
    int cb = i&1;
    #pragma unroll
    for (int kk=0;kk<4;++kk){
      short8 A2[4];
      #pragma unroll
      for (int mt=0;mt<4;++mt)
        A2[mt] = *(const short8*)&HtA[(size_t)(cb*16 + mt*4 + kk)*512 + lane*8];
      #pragma unroll
      for (int et=0;et<2;++et)
        #pragma unroll
        for (int mt=0;mt<4;++mt)
          acc[mt][et] = __builtin_amdgcn_mfma_f32_16x16x32_bf16(A2[mt], B2c[et][kk], acc[mt][et], 0,0,0);
    }
    __syncthreads();
    if (i < 15){
      #pragma unroll
      for (int et=0;et<2;++et)
        #pragma unroll
        for (int kk=0;kk<4;++kk) B2c[et][kk]=B2n[et][kk];
    }
  }

  // epilogue: pre2 = acc + residual; partial LN stats; write hw
  #pragma unroll
  for (int mt=0; mt<4; ++mt){
    #pragma unroll
    for (int r=0;r<4;++r){
      int ltok = mt*16 + quad*4 + r;
      size_t hb = (size_t)(tok0+ltok)*EE + nb*128;
      #pragma unroll
      for (int et=0;et<2;++et){
        int eloc = w*32 + et*16 + col;
        int eg = nb*128 + eloc;
        float rsd = (eg < 16) ? h16[(size_t)(tok0+ltok)*16 + eg] : hw[hb + eloc];
        outL[ltok*132 + eloc] = acc[mt][et][r] + rsd;
      }
    }
  }
  __syncthreads();
  {
    int token = tid>>2, prt = tid&3;
    float s=0.f, s2=0.f;
    #pragma unroll 8
    for (int i2=0;i2<32;++i2){
      float vv = outL[token*132 + prt + 4*i2];
      s += vv; s2 = fmaf(vv,vv,s2);
    }
    s += __shfl_down(s,2,4); s2 += __shfl_down(s2,2,4);
    s += __shfl_down(s,1,4); s2 += __shfl_down(s2,1,4);
    if (prt==0){
      float2 o; o.x = s; o.y = s2;
      *(float2*)&st[((size_t)(tok0+token)*4 + nb)*2] = o;
    }
  }
  for (int u=tid; u<64*32; u+=256){
    int tok = u>>5, c4 = (u&31)*4;
    float4 vv = *(const float4*)&outL[tok*132 + c4];
    *(float4*)&hw[(size_t)(tok0+tok)*EE + nb*128 + c4] = vv;
  }
}

__global__ __launch_bounds__(256) void conv2_k(const float* __restrict__ hw,
    const float* __restrict__ st, const void* __restrict__ g2v,
    const void* __restrict__ b2v, void* __restrict__ out,
    const int* __restrict__ flag){
  int f = *flag;
  size_t i = (size_t)blockIdx.x*256 + threadIdx.x;   // float4 index
  int tok = (int)(i>>7), c4 = ((int)i&127)*4;
  float4 v = *(const float4*)&hw[i*4];
  float m, rs; tok_stats(st, tok, m, rs);
  float4 gv = ldg4(g2v,f,(size_t)3*EE + c4);
  float4 bv = ldg4(b2v,f,(size_t)3*EE + c4);
  float4 o;
  o.x = fmaf((v.x-m)*rs, gv.x, bv.x);
  o.y = fmaf((v.y-m)*rs, gv.y, bv.y);
  o.z = fmaf((v.z-m)*rs, gv.z, bv.z);
  o.w = fmaf((v.w-m)*rs, gv.w, bv.w);
  if (f){
    *(float4*)((float*)out + i*4) = o;
  } else {
    ushort4 ob; ob.x=f2bf(o.x); ob.y=f2bf(o.y); ob.z=f2bf(o.z); ob.w=f2bf(o.w);
    *(ushort4*)((u16*)out + i*4) = ob;
  }
}

extern "C" void kernel_launch(void* const* d_in, const int* in_sizes, int n_in,
                              void* d_out, int out_size, void* d_ws, size_t ws_size,
                              hipStream_t stream) {
  (void)in_sizes; (void)n_in; (void)out_size;
  char* ws = (char*)d_ws;
  int*   flag = (int*)(ws + FLAG_OFF);
  float* h16  = (float*)(ws + H16_OFF);
  float* qf   = (float*)(ws + QF_OFF);
  u16*   w1p  = (u16*)(ws + W1P_OFF);
  float* st   = (float*)(ws + STATS_OFF);
  float* hw   = (float*)(ws + H_OFF);
  u16*   w2p  = (u16*)(ws + W2P_OFF);
  int cv = (ws_size >= (size_t)W2P_OFF + ((size_t)8<<20)) ? 1 : 0;

  detect_k<<<1,256,0,stream>>>((const u16*)d_in[0], flag);
  w1pack_k<<<64,256,0,stream>>>(d_in[5], d_in[3], w1p, flag);
  if (cv) w2pack_k<<<2048,256,0,stream>>>(d_in[6], w2p, flag);
  add_pe_k<<<4096,256,0,stream>>>(d_in[0], d_in[1], hw, flag);
  for (int l=0; l<4; ++l){
    int lazy = (l>0) ? 1 : 0;
    attn_comb_k<<<512,512,0,stream>>>(hw, d_in[2], d_in[4], d_in[7], d_in[8],
                                      d_in[9], d_in[10], st, h16, qf,
                                      flag, lazy, l);
    ffn6_k<<<dim3(128,4),256,0,stream>>>(hw, h16, qf, w1p, d_in[6], w2p,
                                         st, flag, cv, l);
  }
  conv2_k<<<4096,256,0,stream>>>(hw, st, d_in[9], d_in[10], d_out, flag);
}